// Round 4
// baseline (4286.448 us; speedup 1.0000x reference)
//
#include <hip/hip_runtime.h>
#include <hip/hip_bf16.h>

// GRU forward: B=64, T=512, I=512, U=512, out [B,T,U] fp32.
// Arch: x_all precomputed (hi/lo bf16 planes). Scan: 64 persistent WGs =
// 4 batch-groups (M=16 rows) x 16 col-WGs (32 units each). Each col-WG keeps
// its R-slice as MFMA B-fragments (hi+lo) in registers forever.
// Round 4 changes (vs r3, which was 6.8us/step with all pipes <2.5%):
//  - waves 6-7 poll peer flags AND stage h hi/lo (32KB) into LDS once per WG;
//    MFMA waves read A-frags from LDS (was: 6 waves each re-reading the same
//    192KB/step from L3 -> 12MB/step of congestion).
//  - gates write h to LDS; wave 0 alone does coalesced sc1 stores of the two
//    1KB plane chunks, drains ITS OWN vmcnt(0), stores the flag (release
//    without an extra barrier; was: 512 scattered 4B sc1 stores + barrier).
//  - out staged via LDS, stored as 16B chunks by waves 1-2 (was: 512
//    scattered 8B stores draining at the protocol barrier).

typedef float f32x4 __attribute__((ext_vector_type(4)));
typedef float f32x2 __attribute__((ext_vector_type(2)));
typedef short bf16x8 __attribute__((ext_vector_type(8)));
typedef unsigned long long u64;
typedef unsigned int u32;

#define MFMA16(a, b, c) __builtin_amdgcn_mfma_f32_16x16x32_bf16((a), (b), (c), 0, 0, 0)

__device__ __forceinline__ float bf2f(__hip_bfloat16 v) { return __bfloat162float(v); }

__device__ __forceinline__ void split_bf(float v, short& hi, short& lo) {
    __hip_bfloat16 h = __float2bfloat16(v);
    float rem = v - __bfloat162float(h);
    __hip_bfloat16 l = __float2bfloat16(rem);
    hi = __builtin_bit_cast(short, h);
    lo = __builtin_bit_cast(short, l);
}

struct U64x2 {
    u64 a, b;
};

// Device-coherent 16B load as two sc1 dwordx2 loads (agent scope, relaxed).
__device__ __forceinline__ bf16x8 load_frag_sc1(const __hip_bfloat16* p) {
    const u64* q = (const u64*)p;
    U64x2 t;
    t.a = __hip_atomic_load(q, __ATOMIC_RELAXED, __HIP_MEMORY_SCOPE_AGENT);
    t.b = __hip_atomic_load(q + 1, __ATOMIC_RELAXED, __HIP_MEMORY_SCOPE_AGENT);
    return __builtin_bit_cast(bf16x8, t);
}

// Device-coherent 16B store as two sc1 dwordx2 stores.
__device__ __forceinline__ void store_frag_sc1(__hip_bfloat16* p, bf16x8 v) {
    U64x2 t = __builtin_bit_cast(U64x2, v);
    u64* q = (u64*)p;
    __hip_atomic_store(q, t.a, __ATOMIC_RELAXED, __HIP_MEMORY_SCOPE_AGENT);
    __hip_atomic_store(q + 1, t.b, __ATOMIC_RELAXED, __HIP_MEMORY_SCOPE_AGENT);
}

// ---------------------------------------------------------------- zero scratch
__global__ void zero_kernel(float* p, int n) {
    int i = blockIdx.x * blockDim.x + threadIdx.x;
    int stride = gridDim.x * blockDim.x;
    for (; i < n; i += stride) p[i] = 0.f;
}

// ------------------------------------------------- pack weights into B-frags
// Source W [512 x 1536] fp32. Frag (tile,kk): lane l element e =
// W[kk*32 + 8*(l>>4) + e][tile*16 + (l&15)], stored hi/lo bf16 planes.
__global__ __launch_bounds__(64, 1) void pack_w_kernel(const float* __restrict__ W,
                                                       short* __restrict__ dhi,
                                                       short* __restrict__ dlo) {
    int bid = blockIdx.x;   // tile*16 + kk, 0..1535
    int lane = threadIdx.x; // 0..63
    int col = (bid >> 4) * 16 + (lane & 15);
    int kbase = (bid & 15) * 32 + (lane >> 4) * 8;
    bf16x8 vh, vl;
#pragma unroll
    for (int e = 0; e < 8; e++) {
        float v = W[(kbase + e) * 1536 + col];
        short h, l;
        split_bf(v, h, l);
        vh[e] = h;
        vl[e] = l;
    }
    *(bf16x8*)(dhi + bid * 512 + lane * 8) = vh;
    *(bf16x8*)(dlo + bid * 512 + lane * 8) = vl;
}

// ------------------------------------------------------------- x_all GEMM
// x_all[r=b*512+t][1536] = inputs[r][:512] @ kernel + bias[0], hi/lo bf16.
// Block = 4 waves, one 16-row tile; wave w handles col-tiles [24w, 24w+24).
__global__ __launch_bounds__(256, 2) void xgemm_kernel(
    const float* __restrict__ A, const short* __restrict__ wkh,
    const short* __restrict__ wkl, const float* __restrict__ bias,
    __hip_bfloat16* __restrict__ xhi, __hip_bfloat16* __restrict__ xlo, int xlo_en) {
    int rt = blockIdx.x; // 0..2047
    int wave = threadIdx.x >> 6, lane = threadIdx.x & 63;
    int arow = rt * 16 + (lane & 15);
    const float* abase = A + arow * 512 + (lane >> 4) * 8;

    f32x4 acc[24];
#pragma unroll
    for (int j = 0; j < 24; j++) acc[j] = (f32x4){0.f, 0.f, 0.f, 0.f};

#pragma unroll 1
    for (int kk = 0; kk < 16; kk++) {
        f32x4 a0 = *(const f32x4*)(abase + kk * 32);
        f32x4 a1 = *(const f32x4*)(abase + kk * 32 + 4);
        bf16x8 ah, al;
#pragma unroll
        for (int e = 0; e < 8; e++) {
            float v = (e < 4) ? a0[e] : a1[e - 4];
            short h, l;
            split_bf(v, h, l);
            ah[e] = h;
            al[e] = l;
        }
#pragma unroll
        for (int j = 0; j < 24; j++) {
            int frag = (wave * 24 + j) * 16 + kk;
            bf16x8 bh = *(const bf16x8*)(wkh + frag * 512 + lane * 8);
            bf16x8 bl = *(const bf16x8*)(wkl + frag * 512 + lane * 8);
            acc[j] = MFMA16(ah, bh, acc[j]);
            acc[j] = MFMA16(al, bh, acc[j]);
            acc[j] = MFMA16(ah, bl, acc[j]);
        }
    }
    int colin = lane & 15, r4 = (lane >> 4) * 4;
#pragma unroll
    for (int j = 0; j < 24; j++) {
        int colg = (wave * 24 + j) * 16 + colin;
        float bv = bias[colg];
#pragma unroll
        for (int r = 0; r < 4; r++) {
            float v = acc[j][r] + bv;
            int rowg = rt * 16 + r4 + r;
            short h, l;
            split_bf(v, h, l);
            xhi[rowg * 1536 + colg] = __builtin_bit_cast(__hip_bfloat16, h);
            if (xlo_en) xlo[rowg * 1536 + colg] = __builtin_bit_cast(__hip_bfloat16, l);
        }
    }
}

// ------------------------------------------------------------------ scan
// 64 blocks x 512 threads. block: g = bid&3 (batch group, rows 16g..16g+15),
// w = bid>>2 (units 32w..32w+31; col-tiles z:{2w,2w+1} r:{32+..} h:{64+..}).
// Waves 0-5: MFMA (one tile each, R-slice in regs). Waves 6-7: flag poll +
// h->LDS staging (phase A) and x[t+1] prefetch (phase B).
// Threads 0-255: gates, 2 units each.
__global__ __launch_bounds__(512, 2) void scan_kernel(
    const __hip_bfloat16* __restrict__ xhi, const __hip_bfloat16* __restrict__ xlo,
    const short* __restrict__ wrh, const short* __restrict__ wrl,
    const float* __restrict__ bias, float* __restrict__ out,
    __hip_bfloat16* hbuf, int* flags, int xlo_en) {
    const int bid = blockIdx.x;
    const int g = bid & 3;
    const int w = bid >> 2;
    const int tid = threadIdx.x;
    const int wave = tid >> 6;
    const int lane = tid & 63;

    __shared__ __align__(16) float pre[6][16][16];
    __shared__ __align__(16) __hip_bfloat16 xsh[2][2][16][104]; // [parity][plane]
    __shared__ __align__(16) __hip_bfloat16 hsh[2][16][512];    // [plane][kk][frag] 32KB
    __shared__ __align__(16) u32 hstu[2][256];                  // staged h (hi/lo packed)
    __shared__ __align__(16) float hstout[16][36];              // staged fp32 out
    __shared__ float rb[96];

    if (tid < 96) {
        int seg = tid >> 5, u = tid & 31;
        rb[tid] = bias[1536 + seg * 512 + w * 32 + u];
    }

    // persistent B fragments (hi+lo) for waves 0-5
    bf16x8 bh[16], bl[16];
    if (wave < 6) {
        int tile = (wave >> 1) * 32 + 2 * w + (wave & 1);
#pragma unroll
        for (int kk = 0; kk < 16; kk++) {
            bh[kk] = *(const bf16x8*)(wrh + (tile * 16 + kk) * 512 + lane * 8);
            bl[kk] = *(const bf16x8*)(wrl + (tile * 16 + kk) * 512 + lane * 8);
        }
    } else {
        // initial prefetch of x[0] into xsh[0]
        int it = tid - 384; // 0..127
        int nch = xlo_en ? 384 : 192;
        for (int c = it; c < nch; c += 128) {
            int plane = c / 192;
            int rem = c % 192;
            int row_ = rem / 12;
            int cw = rem % 12;
            int seg = cw >> 2, off = cw & 3;
            int rglob = (g * 16 + row_) * 512 + 0;
            const __hip_bfloat16* src =
                (plane ? xlo : xhi) + rglob * 1536 + seg * 512 + w * 32 + off * 8;
            *(bf16x8*)&xsh[0][plane][row_][seg * 32 + off * 8] = *(const bf16x8*)src;
        }
    }

    const int grow = tid & 15; // gate thread: batch row
    const int q = tid >> 4;    // gate thread: unit pair 0..15 (tid<256)
    float h0 = 0.f, h1 = 0.f;

    __syncthreads();

    const int HB = 8192; // plane stride (elems): 16 chunks * 512
    for (int t = 0; t < 512; t++) {
        const int rpar = t & 1;
        // -------- stage phase: waves 6-7 poll peers, stage h[rpar] -> LDS ----
        if (wave >= 6) {
            if (t > 0) {
                const int fidx = (g * 16 + (lane & 15)) * 16;
                long spins = 0;
                while (true) {
                    int f = (lane < 16)
                                ? __hip_atomic_load(&flags[fidx], __ATOMIC_RELAXED,
                                                    __HIP_MEMORY_SCOPE_AGENT)
                                : t;
                    if (__all(f >= t)) break;
                    if (++spins > (1L << 22)) break; // bailout (never hit if correct)
                }
            }
            int plane = wave - 6; // wave6: hi, wave7: lo
            const __hip_bfloat16* src = hbuf + ((rpar * 4 + g) * 2 + plane) * HB;
#pragma unroll
            for (int c = 0; c < 16; c++) {
                bf16x8 v = load_frag_sc1(src + c * 512 + lane * 8);
                *(bf16x8*)&hsh[plane][c][lane * 8] = v;
            }
        }
        __syncthreads(); // B2: h staged
        // -------- phase A: MFMA from LDS --------
        if (wave < 6) {
            f32x4 aa = (f32x4){0.f, 0.f, 0.f, 0.f};
            f32x4 ab = (f32x4){0.f, 0.f, 0.f, 0.f};
            f32x4 ac = (f32x4){0.f, 0.f, 0.f, 0.f};
#pragma unroll
            for (int kk = 0; kk < 16; kk++) {
                bf16x8 ah = *(const bf16x8*)&hsh[0][kk][lane * 8];
                bf16x8 al = *(const bf16x8*)&hsh[1][kk][lane * 8];
                aa = MFMA16(ah, bh[kk], aa);
                ab = MFMA16(al, bh[kk], ab);
                ac = MFMA16(ah, bl[kk], ac);
            }
            f32x4 acc = aa + ab;
            acc = acc + ac;
            int col = lane & 15, r4 = (lane >> 4) * 4;
            *(f32x4*)&pre[wave][col][r4] = acc;
        }
        __syncthreads(); // B3: pre ready
        // -------- phase B: gates (waves 0-3) + x[t+1] prefetch (waves 6-7) ---
        if (tid < 256) {
            float hold[2] = {h0, h1};
            float hn[2];
#pragma unroll
            for (int j = 0; j < 2; j++) {
                int uu = 2 * q + j;
                int slot = uu >> 4, c16 = uu & 15;
                float xz = bf2f(xsh[rpar][0][grow][uu]);
                float xr = bf2f(xsh[rpar][0][grow][32 + uu]);
                float xh = bf2f(xsh[rpar][0][grow][64 + uu]);
                if (xlo_en) {
                    xz += bf2f(xsh[rpar][1][grow][uu]);
                    xr += bf2f(xsh[rpar][1][grow][32 + uu]);
                    xh += bf2f(xsh[rpar][1][grow][64 + uu]);
                }
                float rz = pre[slot][c16][grow] + rb[uu];
                float rr = pre[2 + slot][c16][grow] + rb[32 + uu];
                float rh = pre[4 + slot][c16][grow] + rb[64 + uu];
                float z = 1.f / (1.f + expf(-(xz + rz)));
                float r = 1.f / (1.f + expf(-(xr + rr)));
                float hh = tanhf(xh + r * rh);
                hn[j] = z * hold[j] + (1.f - z) * hh;
            }
            h0 = hn[0];
            h1 = hn[1];
            // stage h (frag layout) and out into LDS
            short hi0, lo0, hi1, lo1;
            split_bf(hn[0], hi0, lo0);
            split_bf(hn[1], hi1, lo1);
            const int wlane = grow + 16 * (q >> 2);
            const int uidx = wlane * 4 + (q & 3);
            hstu[0][uidx] = (u32)(unsigned short)hi0 | ((u32)(unsigned short)hi1 << 16);
            hstu[1][uidx] = (u32)(unsigned short)lo0 | ((u32)(unsigned short)lo1 << 16);
            *(f32x2*)&hstout[grow][2 * q] = (f32x2){hn[0], hn[1]};
        } else if (wave >= 6 && t + 1 < 512) {
            int it = tid - 384; // 0..127
            int nch = xlo_en ? 384 : 192;
            int npar = 1 - rpar;
            for (int c = it; c < nch; c += 128) {
                int plane = c / 192;
                int rem = c % 192;
                int row_ = rem / 12;
                int cw = rem % 12;
                int seg = cw >> 2, off = cw & 3;
                int rglob = (g * 16 + row_) * 512 + (t + 1);
                const __hip_bfloat16* src =
                    (plane ? xlo : xhi) + rglob * 1536 + seg * 512 + w * 32 + off * 8;
                *(bf16x8*)&xsh[npar][plane][row_][seg * 32 + off * 8] =
                    *(const bf16x8*)src;
            }
        }
        __syncthreads(); // B4: hstu/hstout ready
        // -------- global stores --------
        if (wave == 0 && t < 511) {
            // wave 0 stores BOTH h plane chunks (coalesced), drains own vmcnt,
            // then lane 0 stores the flag: release without an extra barrier.
            const int wpar = 1 - rpar;
            __hip_bfloat16* dst = hbuf + (wpar * 4 + g) * 2 * HB + w * 512;
            bf16x8 vh = *(bf16x8*)&hstu[0][lane * 4];
            bf16x8 vl = *(bf16x8*)&hstu[1][lane * 4];
            store_frag_sc1(dst + lane * 8, vh);
            store_frag_sc1(dst + HB + lane * 8, vl);
            asm volatile("s_waitcnt vmcnt(0)" ::: "memory");
            if (lane == 0) {
                __hip_atomic_store(&flags[(g * 16 + w) * 16], t + 1, __ATOMIC_RELAXED,
                                   __HIP_MEMORY_SCOPE_AGENT);
            }
        }
        if (wave == 1 || wave == 2) {
            int row = (wave - 1) * 8 + (lane >> 3);
            int c4 = lane & 7;
            f32x4 v = *(f32x4*)&hstout[row][c4 * 4];
            *(f32x4*)&out[((size_t)(g * 16 + row) * 512 + t) * 512 + w * 32 + c4 * 4] = v;
        }
    }
}

extern "C" void kernel_launch(void* const* d_in, const int* in_sizes, int n_in,
                              void* d_out, int out_size, void* d_ws, size_t ws_size,
                              hipStream_t stream) {
    const float* inputs = (const float*)d_in[0]; // [64,512,512]
    const float* wk = (const float*)d_in[1];     // [512,1536]
    const float* wr = (const float*)d_in[2];     // [512,1536]
    const float* bias = (const float*)d_in[3];   // [2,1536]
    float* out = (float*)d_out;
    char* ws = (char*)d_ws;

    const size_t SZ_W = 512UL * 1536 * 2; // 1.5 MiB per plane
    short* wk_hi = (short*)(ws);
    short* wk_lo = (short*)(ws + SZ_W);
    short* wr_hi = (short*)(ws + 2 * SZ_W);
    short* wr_lo = (short*)(ws + 3 * SZ_W);
    __hip_bfloat16* hbuf = (__hip_bfloat16*)(ws + 4 * SZ_W); // 256 KiB
    int* flags = (int*)(ws + 4 * SZ_W + 262144);             // 4 KiB (64 x 64B)
    char* xbase = ws + 4 * SZ_W + 262144 + 8192;
    const size_t SZ_X = 32768UL * 1536 * 2; // 96 MiB per plane
    __hip_bfloat16* xhi = (__hip_bfloat16*)xbase;
    __hip_bfloat16* xlo = (__hip_bfloat16*)(xbase + SZ_X);

    size_t need_min = (size_t)(xbase - ws) + SZ_X;
    size_t need_full = need_min + SZ_X;
    if (ws_size < need_min) return; // cannot run without scratch; fail visibly
    int xlo_en = (ws_size >= need_full) ? 1 : 0;

    zero_kernel<<<256, 256, 0, stream>>>((float*)hbuf, (262144 + 8192) / 4);
    pack_w_kernel<<<1536, 64, 0, stream>>>(wk, wk_hi, wk_lo);
    pack_w_kernel<<<1536, 64, 0, stream>>>(wr, wr_hi, wr_lo);
    xgemm_kernel<<<2048, 256, 0, stream>>>(inputs, wk_hi, wk_lo, bias, xhi, xlo, xlo_en);
    scan_kernel<<<64, 512, 0, stream>>>(xhi, xlo, wr_hi, wr_lo, bias, out, hbuf, flags,
                                        xlo_en);
}

// Round 6
// 3683.920 us; speedup vs baseline: 1.1636x; 1.1636x over previous
//
#include <hip/hip_runtime.h>
#include <hip/hip_bf16.h>

// GRU forward: B=64, T=512, I=512, U=512, out [B,T,U] fp32.
// Round 6 = round 2 (best known good, 3277us) + two isolated fixes:
//  (a) B-fragments pinned in VGPRs via asm "+v" — r4 counters proved
//      (VGPR_Count=96 < 128 frag regs, FETCH 272MB > 192MB x-planes) that the
//      compiler rematerialized the 64KB/WG weight loads EVERY step inside the
//      MFMA phase.
//  (b) out stores deferred past the barrier+counter increment — out is
//      write-only, so its HBM ack now overlaps the poll window instead of
//      delaying the release.
// Everything else identical to round 2: 64 persistent WGs = 4 groups
// (16 batch rows) x 16 col-WGs (32 units); sc1 (device-coherent) relaxed
// atomics for h exchange; per-(group,step) counter + s_sleep poll by tid 0.

typedef float f32x4 __attribute__((ext_vector_type(4)));
typedef short bf16x8 __attribute__((ext_vector_type(8)));
typedef unsigned long long u64;
typedef unsigned int u32;

#define MFMA16(a, b, c) __builtin_amdgcn_mfma_f32_16x16x32_bf16((a), (b), (c), 0, 0, 0)

__device__ __forceinline__ float bf2f(__hip_bfloat16 v) { return __bfloat162float(v); }

__device__ __forceinline__ void split_bf(float v, short& hi, short& lo) {
    __hip_bfloat16 h = __float2bfloat16(v);
    float rem = v - __bfloat162float(h);
    __hip_bfloat16 l = __float2bfloat16(rem);
    hi = __builtin_bit_cast(short, h);
    lo = __builtin_bit_cast(short, l);
}

struct U64x2 {
    u64 a, b;
};

// Device-coherent 16B load as two sc1 dwordx2 loads (agent scope, relaxed).
__device__ __forceinline__ bf16x8 load_frag_sc1(const __hip_bfloat16* p) {
    const u64* q = (const u64*)p;
    U64x2 t;
    t.a = __hip_atomic_load(q, __ATOMIC_RELAXED, __HIP_MEMORY_SCOPE_AGENT);
    t.b = __hip_atomic_load(q + 1, __ATOMIC_RELAXED, __HIP_MEMORY_SCOPE_AGENT);
    return __builtin_bit_cast(bf16x8, t);
}

__device__ __forceinline__ void store_pair_sc1(__hip_bfloat16* p, short e0, short e1) {
    u32 v = (u32)(unsigned short)e0 | ((u32)(unsigned short)e1 << 16);
    __hip_atomic_store((u32*)p, v, __ATOMIC_RELAXED, __HIP_MEMORY_SCOPE_AGENT);
}

// ---------------------------------------------------------------- zero scratch
__global__ void zero_kernel(float* p, int n) {
    int i = blockIdx.x * blockDim.x + threadIdx.x;
    int stride = gridDim.x * blockDim.x;
    for (; i < n; i += stride) p[i] = 0.f;
}

// ------------------------------------------------- pack weights into B-frags
// Source W [512 x 1536] fp32. Frag (tile,kk): lane l element e =
// W[kk*32 + 8*(l>>4) + e][tile*16 + (l&15)], stored hi/lo bf16 planes.
__global__ __launch_bounds__(64, 1) void pack_w_kernel(const float* __restrict__ W,
                                                       short* __restrict__ dhi,
                                                       short* __restrict__ dlo) {
    int bid = blockIdx.x;   // tile*16 + kk, 0..1535
    int lane = threadIdx.x; // 0..63
    int col = (bid >> 4) * 16 + (lane & 15);
    int kbase = (bid & 15) * 32 + (lane >> 4) * 8;
    bf16x8 vh, vl;
#pragma unroll
    for (int e = 0; e < 8; e++) {
        float v = W[(kbase + e) * 1536 + col];
        short h, l;
        split_bf(v, h, l);
        vh[e] = h;
        vl[e] = l;
    }
    *(bf16x8*)(dhi + bid * 512 + lane * 8) = vh;
    *(bf16x8*)(dlo + bid * 512 + lane * 8) = vl;
}

// ------------------------------------------------------------- x_all GEMM
// x_all[r=b*512+t][1536] = inputs[r][:512] @ kernel + bias[0], hi/lo bf16.
// Block = 4 waves, one 16-row tile; wave w handles col-tiles [24w, 24w+24).
__global__ __launch_bounds__(256, 2) void xgemm_kernel(
    const float* __restrict__ A, const short* __restrict__ wkh,
    const short* __restrict__ wkl, const float* __restrict__ bias,
    __hip_bfloat16* __restrict__ xhi, __hip_bfloat16* __restrict__ xlo, int xlo_en) {
    int rt = blockIdx.x; // 0..2047
    int wave = threadIdx.x >> 6, lane = threadIdx.x & 63;
    int arow = rt * 16 + (lane & 15);
    const float* abase = A + arow * 512 + (lane >> 4) * 8;

    f32x4 acc[24];
#pragma unroll
    for (int j = 0; j < 24; j++) acc[j] = (f32x4){0.f, 0.f, 0.f, 0.f};

#pragma unroll 1
    for (int kk = 0; kk < 16; kk++) {
        f32x4 a0 = *(const f32x4*)(abase + kk * 32);
        f32x4 a1 = *(const f32x4*)(abase + kk * 32 + 4);
        bf16x8 ah, al;
#pragma unroll
        for (int e = 0; e < 8; e++) {
            float v = (e < 4) ? a0[e] : a1[e - 4];
            short h, l;
            split_bf(v, h, l);
            ah[e] = h;
            al[e] = l;
        }
#pragma unroll
        for (int j = 0; j < 24; j++) {
            int frag = (wave * 24 + j) * 16 + kk;
            bf16x8 bh = *(const bf16x8*)(wkh + frag * 512 + lane * 8);
            bf16x8 bl = *(const bf16x8*)(wkl + frag * 512 + lane * 8);
            acc[j] = MFMA16(ah, bh, acc[j]);
            acc[j] = MFMA16(al, bh, acc[j]);
            acc[j] = MFMA16(ah, bl, acc[j]);
        }
    }
    int colin = lane & 15, r4 = (lane >> 4) * 4;
#pragma unroll
    for (int j = 0; j < 24; j++) {
        int colg = (wave * 24 + j) * 16 + colin;
        float bv = bias[colg];
#pragma unroll
        for (int r = 0; r < 4; r++) {
            float v = acc[j][r] + bv;
            int rowg = rt * 16 + r4 + r;
            short h, l;
            split_bf(v, h, l);
            xhi[rowg * 1536 + colg] = __builtin_bit_cast(__hip_bfloat16, h);
            if (xlo_en) xlo[rowg * 1536 + colg] = __builtin_bit_cast(__hip_bfloat16, l);
        }
    }
}

// ------------------------------------------------------------------ scan
// 64 blocks x 512 threads. block: g = bid&3 (batch group, rows 16g..16g+15),
// w = bid>>2 (units 32w..32w+31; col-tiles z:{2w,2w+1} r:{32+..} h:{64+..}).
// Waves 0-5: MFMA (one tile each, R-slice PINNED in regs). Waves 6-7: x
// prefetch. Threads 0-255: gates, 2 units each; persistent fp32 h in regs.
__global__ __launch_bounds__(512, 2) void scan_kernel(
    const __hip_bfloat16* __restrict__ xhi, const __hip_bfloat16* __restrict__ xlo,
    const short* __restrict__ wrh, const short* __restrict__ wrl,
    const float* __restrict__ bias, float* __restrict__ out,
    __hip_bfloat16* hbuf, int* cnt, int xlo_en) {
    const int bid = blockIdx.x;
    const int g = bid & 3;
    const int w = bid >> 2;
    const int tid = threadIdx.x;
    const int wave = tid >> 6;
    const int lane = tid & 63;

    __shared__ __align__(16) float pre[6][16][16];
    __shared__ __align__(16) __hip_bfloat16 xsh[2][16][104]; // padded stride
    __shared__ float rb[96];

    if (tid < 96) {
        int seg = tid >> 5, u = tid & 31;
        rb[tid] = bias[1536 + seg * 512 + w * 32 + u];
    }

    // persistent B fragments (hi+lo) for waves 0-5
    bf16x8 bh[16], bl[16];
    if (wave < 6) {
        int tile = (wave >> 1) * 32 + 2 * w + (wave & 1);
#pragma unroll
        for (int kk = 0; kk < 16; kk++) {
            bh[kk] = *(const bf16x8*)(wrh + (tile * 16 + kk) * 512 + lane * 8);
            bl[kk] = *(const bf16x8*)(wrl + (tile * 16 + kk) * 512 + lane * 8);
        }
        // Pin: opaque def kills rematerialization of the weight loads (r4
        // counters: VGPR_Count=96 proved the compiler reloaded these every
        // step inside the MFMA phase).
#pragma unroll
        for (int kk = 0; kk < 16; kk++) {
            asm volatile("" : "+v"(bh[kk]), "+v"(bl[kk]));
        }
    }

    const int grow = tid & 15; // gate thread: batch row
    const int q = tid >> 4;    // gate thread: unit pair 0..15 (tid<256)
    float h0 = 0.f, h1 = 0.f;
    const int wlane = grow + 16 * (q >> 2); // frag lane for h writes
    const int woff = (2 * q) & 7;           // element offset in frag lane

    __syncthreads();

    const int HB = 8192; // plane stride (elems): 16 kk * 64 lanes * 8
    for (int t = 0; t < 512; t++) {
        const int rpar = t & 1;
        // ---------------- phase A: MFMA + x prefetch ----------------
        if (wave < 6) {
            const __hip_bfloat16* hH = hbuf + (rpar * 4 + g) * 2 * HB;
            const __hip_bfloat16* hL = hH + HB;
            f32x4 aa = (f32x4){0.f, 0.f, 0.f, 0.f};
            f32x4 ab = (f32x4){0.f, 0.f, 0.f, 0.f};
            f32x4 ac = (f32x4){0.f, 0.f, 0.f, 0.f};
#pragma unroll
            for (int kk = 0; kk < 16; kk++) {
                bf16x8 ah = load_frag_sc1(hH + kk * 512 + lane * 8);
                bf16x8 al = load_frag_sc1(hL + kk * 512 + lane * 8);
                aa = MFMA16(ah, bh[kk], aa);
                ab = MFMA16(al, bh[kk], ab);
                ac = MFMA16(ah, bl[kk], ac);
            }
            f32x4 acc = aa + ab;
            acc = acc + ac;
            int col = lane & 15, r4 = (lane >> 4) * 4;
            *(f32x4*)&pre[wave][col][r4] = acc;
        } else {
            int it = tid - 384; // 0..127
            int nch = xlo_en ? 384 : 192;
            for (int c = it; c < nch; c += 128) {
                int plane = c / 192;
                int rem = c % 192;
                int row_ = rem / 12;
                int cw = rem % 12;
                int seg = cw >> 2, off = cw & 3;
                int rglob = (g * 16 + row_) * 512 + t;
                const __hip_bfloat16* src =
                    (plane ? xlo : xhi) + rglob * 1536 + seg * 512 + w * 32 + off * 8;
                *(bf16x8*)&xsh[plane][row_][seg * 32 + off * 8] = *(const bf16x8*)src;
            }
        }
        __syncthreads();
        // ---------------- phase B: gates (h stores only; out deferred) -------
        if (tid < 256) {
            const int wpar = 1 - rpar;
            __hip_bfloat16* hw =
                hbuf + ((wpar * 4 + g) * 2 + 0) * HB + w * 512 + wlane * 8 + woff;
            __hip_bfloat16* hwl = hw + HB;
            float hold[2] = {h0, h1};
            float hn[2];
#pragma unroll
            for (int j = 0; j < 2; j++) {
                int uu = 2 * q + j;
                int slot = uu >> 4, c16 = uu & 15;
                float xz = bf2f(xsh[0][grow][uu]);
                float xr = bf2f(xsh[0][grow][32 + uu]);
                float xh = bf2f(xsh[0][grow][64 + uu]);
                if (xlo_en) {
                    xz += bf2f(xsh[1][grow][uu]);
                    xr += bf2f(xsh[1][grow][32 + uu]);
                    xh += bf2f(xsh[1][grow][64 + uu]);
                }
                float rz = pre[slot][c16][grow] + rb[uu];
                float rr = pre[2 + slot][c16][grow] + rb[32 + uu];
                float rh = pre[4 + slot][c16][grow] + rb[64 + uu];
                float z = 1.f / (1.f + expf(-(xz + rz)));
                float r = 1.f / (1.f + expf(-(xr + rr)));
                float hh = tanhf(xh + r * rh);
                hn[j] = z * hold[j] + (1.f - z) * hh;
            }
            h0 = hn[0];
            h1 = hn[1];
            short hi0, lo0, hi1, lo1;
            split_bf(hn[0], hi0, lo0);
            split_bf(hn[1], hi1, lo1);
            store_pair_sc1(hw, hi0, hi1);
            store_pair_sc1(hwl, lo0, lo1);
        }
        if (t == 511) {
            // final step: no release needed, just write out and exit
            if (tid < 256) {
                int obase = ((g * 16 + grow) * 512 + t) * 512 + w * 32 + 2 * q;
                out[obase] = h0;
                out[obase + 1] = h1;
            }
            break;
        }
        // __syncthreads drains vmcnt(0) for ALL threads' sc1 h-stores (device
        // visible on completion), so tid 0's relaxed increment is a release in
        // effect without any L2 writeback. out stores are NOT yet issued, so
        // the drain covers only the 2KB of h traffic.
        __syncthreads();
        if (tid == 0) {
            int idx = g * 512 + t;
            __hip_atomic_fetch_add(&cnt[idx], 1, __ATOMIC_RELAXED, __HIP_MEMORY_SCOPE_AGENT);
        }
        // deferred out stores: issued now, drain overlaps tid 0's poll below
        if (tid < 256) {
            int obase = ((g * 16 + grow) * 512 + t) * 512 + w * 32 + 2 * q;
            out[obase] = h0;
            out[obase + 1] = h1;
        }
        if (tid == 0) {
            int idx = g * 512 + t;
            long spins = 0;
            while (__hip_atomic_load(&cnt[idx], __ATOMIC_RELAXED, __HIP_MEMORY_SCOPE_AGENT) <
                   16) {
                if (++spins > (1L << 24)) break; // bailout (never hit if correct)
                __builtin_amdgcn_s_sleep(1);
            }
        }
        __syncthreads();
    }
}

extern "C" void kernel_launch(void* const* d_in, const int* in_sizes, int n_in,
                              void* d_out, int out_size, void* d_ws, size_t ws_size,
                              hipStream_t stream) {
    const float* inputs = (const float*)d_in[0]; // [64,512,512]
    const float* wk = (const float*)d_in[1];     // [512,1536]
    const float* wr = (const float*)d_in[2];     // [512,1536]
    const float* bias = (const float*)d_in[3];   // [2,1536]
    float* out = (float*)d_out;
    char* ws = (char*)d_ws;

    const size_t SZ_W = 512UL * 1536 * 2; // 1.5 MiB per plane
    short* wk_hi = (short*)(ws);
    short* wk_lo = (short*)(ws + SZ_W);
    short* wr_hi = (short*)(ws + 2 * SZ_W);
    short* wr_lo = (short*)(ws + 3 * SZ_W);
    __hip_bfloat16* hbuf = (__hip_bfloat16*)(ws + 4 * SZ_W); // 256 KiB
    int* cnt = (int*)(ws + 4 * SZ_W + 262144);               // 8 KiB
    char* xbase = ws + 4 * SZ_W + 262144 + 8192;
    const size_t SZ_X = 32768UL * 1536 * 2; // 96 MiB per plane
    __hip_bfloat16* xhi = (__hip_bfloat16*)xbase;
    __hip_bfloat16* xlo = (__hip_bfloat16*)(xbase + SZ_X);

    size_t need_min = (size_t)(xbase - ws) + SZ_X;
    size_t need_full = need_min + SZ_X;
    if (ws_size < need_min) return; // cannot run without scratch; fail visibly
    int xlo_en = (ws_size >= need_full) ? 1 : 0;

    zero_kernel<<<256, 256, 0, stream>>>((float*)hbuf, (262144 + 8192) / 4);
    pack_w_kernel<<<1536, 64, 0, stream>>>(wk, wk_hi, wk_lo);
    pack_w_kernel<<<1536, 64, 0, stream>>>(wr, wr_hi, wr_lo);
    xgemm_kernel<<<2048, 256, 0, stream>>>(inputs, wk_hi, wk_lo, bias, xhi, xlo, xlo_en);
    scan_kernel<<<64, 512, 0, stream>>>(xhi, xlo, wr_hi, wr_lo, bias, out, hbuf, cnt,
                                        xlo_en);
}